// Round 1
// baseline (388.336 us; speedup 1.0000x reference)
//
#include <hip/hip_runtime.h>
#include <math.h>

#define NTRAIN 16384
#define DIM 64
#define ODIM 8
#define BATCH 8192

// ---------------------------------------------------------------------------
// Kernel 0: x2[n] = sum_k x_training[n,k]^2   (one thread per training row)
// ---------------------------------------------------------------------------
__global__ __launch_bounds__(256) void grnn_x2_kernel(
    const float* __restrict__ xt, float* __restrict__ x2) {
  int n = blockIdx.x * 256 + threadIdx.x;
  if (n >= NTRAIN) return;
  const float4* row = reinterpret_cast<const float4*>(xt + (size_t)n * DIM);
  float s0 = 0.f, s1 = 0.f, s2 = 0.f, s3 = 0.f;
#pragma unroll
  for (int q = 0; q < DIM / 4; ++q) {
    float4 v = row[q];
    s0 = fmaf(v.x, v.x, s0);
    s1 = fmaf(v.y, v.y, s1);
    s2 = fmaf(v.z, v.z, s2);
    s3 = fmaf(v.w, v.w, s3);
  }
  x2[n] = (s0 + s1) + (s2 + s3);
}

// ---------------------------------------------------------------------------
// Pass 1: each thread owns one batch row (64 floats in VGPRs), iterates over a
// chunk of training points. Training-row data is wave-uniform -> scalar loads.
// Writes partial sums [chunk][9][BATCH] (9 = 1 denom + 8 weighted-y).
// ---------------------------------------------------------------------------
__global__ __launch_bounds__(256) void grnn_pass1(
    const float* __restrict__ batches, const float* __restrict__ xt,
    const float* __restrict__ yt, const float* __restrict__ beta,
    const float* __restrict__ x2, float* __restrict__ partial, int chunk_n) {
  const int bt = blockIdx.x;      // batch tile 0..31
  const int c  = blockIdx.y;      // N-chunk index
  const int b  = bt * 256 + threadIdx.x;

  // Load my batch row into registers + compute its squared norm.
  float a[DIM];
  float b2p0 = 0.f, b2p1 = 0.f, b2p2 = 0.f, b2p3 = 0.f;
  const float4* arow = reinterpret_cast<const float4*>(batches + (size_t)b * DIM);
#pragma unroll
  for (int q = 0; q < DIM / 4; ++q) {
    float4 v = arow[q];
    a[4 * q + 0] = v.x; a[4 * q + 1] = v.y;
    a[4 * q + 2] = v.z; a[4 * q + 3] = v.w;
    b2p0 = fmaf(v.x, v.x, b2p0);
    b2p1 = fmaf(v.y, v.y, b2p1);
    b2p2 = fmaf(v.z, v.z, b2p2);
    b2p3 = fmaf(v.w, v.w, b2p3);
  }
  const float b2 = (b2p0 + b2p1) + (b2p2 + b2p3);

  float acc1 = 0.f;
  float acc2[ODIM];
#pragma unroll
  for (int j = 0; j < ODIM; ++j) acc2[j] = 0.f;

  const int n0 = c * chunk_n;
  const int n1 = n0 + chunk_n;
  for (int n = n0; n < n1; ++n) {
    // Force wave-uniform index so x/y/beta reads become scalar (SGPR) loads.
    const int nu = __builtin_amdgcn_readfirstlane(n);
    const float* __restrict__ xr = xt + (size_t)nu * DIM;

    float d0 = 0.f, d1 = 0.f, d2 = 0.f, d3 = 0.f;
#pragma unroll
    for (int k = 0; k < DIM; k += 4) {
      d0 = fmaf(a[k + 0], xr[k + 0], d0);
      d1 = fmaf(a[k + 1], xr[k + 1], d1);
      d2 = fmaf(a[k + 2], xr[k + 2], d2);
      d3 = fmaf(a[k + 3], xr[k + 3], d3);
    }
    const float dot = (d0 + d1) + (d2 + d3);
    const float sq = fmaxf(b2 + x2[nu] - 2.f * dot, 0.f);
    const float dist = sqrtf(sq);
    const float w = __expf(-beta[nu] * dist);

    acc1 += w;
    const float* __restrict__ yr = yt + (size_t)nu * ODIM;
#pragma unroll
    for (int j = 0; j < ODIM; ++j) acc2[j] = fmaf(w, yr[j], acc2[j]);
  }

  float* __restrict__ p = partial + (size_t)c * 9 * BATCH;
  p[b] = acc1;
#pragma unroll
  for (int j = 0; j < ODIM; ++j) p[(size_t)(1 + j) * BATCH + b] = acc2[j];
}

// ---------------------------------------------------------------------------
// Pass 2: reduce over chunks, divide, write [BATCH, ODIM] fp32 output.
// ---------------------------------------------------------------------------
__global__ __launch_bounds__(256) void grnn_pass2(
    const float* __restrict__ partial, float* __restrict__ out, int nc) {
  const int b = blockIdx.x * 256 + threadIdx.x;
  float s1 = 0.f;
  float s2[ODIM];
#pragma unroll
  for (int j = 0; j < ODIM; ++j) s2[j] = 0.f;
  for (int c = 0; c < nc; ++c) {
    const float* __restrict__ p = partial + (size_t)c * 9 * BATCH;
    s1 += p[b];
#pragma unroll
    for (int j = 0; j < ODIM; ++j) s2[j] += p[(size_t)(1 + j) * BATCH + b];
  }
  const float inv = 1.f / s1;
#pragma unroll
  for (int j = 0; j < ODIM; ++j) out[(size_t)b * ODIM + j] = s2[j] * inv;
}

// ---------------------------------------------------------------------------
extern "C" void kernel_launch(void* const* d_in, const int* in_sizes, int n_in,
                              void* d_out, int out_size, void* d_ws, size_t ws_size,
                              hipStream_t stream) {
  const float* batches = (const float*)d_in[0];  // [8192, 64]
  const float* xt      = (const float*)d_in[1];  // [16384, 64]
  const float* yt      = (const float*)d_in[2];  // [16384, 8]
  const float* beta    = (const float*)d_in[3];  // [1, 16384]
  float* out = (float*)d_out;                    // [8192, 8]

  // Pick the largest N-chunk count whose partial buffer (+ x2) fits in d_ws.
  int nc = 32;
  while (nc > 1) {
    size_t need = ((size_t)nc * 9 * BATCH + NTRAIN) * sizeof(float);
    if (need <= ws_size) break;
    nc >>= 1;
  }
  const int chunk_n = NTRAIN / nc;

  float* partial = (float*)d_ws;
  float* x2 = partial + (size_t)nc * 9 * BATCH;

  grnn_x2_kernel<<<NTRAIN / 256, 256, 0, stream>>>(xt, x2);
  grnn_pass1<<<dim3(BATCH / 256, nc), 256, 0, stream>>>(
      batches, xt, yt, beta, x2, partial, chunk_n);
  grnn_pass2<<<BATCH / 256, 256, 0, stream>>>(partial, out, nc);
}

// Round 3
// 109.463 us; speedup vs baseline: 3.5476x; 3.5476x over previous
//
#include <hip/hip_runtime.h>
#include <math.h>
#include <stdint.h>

#define NTRAIN 16384
#define DIM 64
#define ODIM 8
#define BATCH 8192

typedef float f32x4 __attribute__((ext_vector_type(4)));
typedef short short8 __attribute__((ext_vector_type(8)));
typedef unsigned short u16;

// float -> bf16 bits, round-to-nearest-even (no NaN in this data)
static __device__ __forceinline__ u16 f2bf(float f) {
  unsigned u = __builtin_bit_cast(unsigned, f);
  u += 0x7FFFu + ((u >> 16) & 1u);
  return (u16)(u >> 16);
}
static __device__ __forceinline__ float bf2f(u16 b) {
  unsigned u = ((unsigned)b) << 16;
  return __builtin_bit_cast(float, u);
}

static __device__ __forceinline__ f32x4 mfma16(short8 a, short8 b, f32x4 c) {
  return __builtin_amdgcn_mfma_f32_16x16x32_bf16(a, b, c, 0, 0, 0);
}

// ---------------------------------------------------------------------------
// b2[i] = |batches[i]|^2 ; x2[i] = |x_training[i]|^2
// ---------------------------------------------------------------------------
__global__ __launch_bounds__(256) void k_norm(const float* __restrict__ batches,
                                              const float* __restrict__ xt,
                                              float* __restrict__ b2,
                                              float* __restrict__ x2) {
  int i = blockIdx.x * 256 + threadIdx.x;
  const float* row;
  float* dst;
  if (i < BATCH) { row = batches + (size_t)i * DIM; dst = b2 + i; }
  else if (i < BATCH + NTRAIN) { row = xt + (size_t)(i - BATCH) * DIM; dst = x2 + (i - BATCH); }
  else return;
  const float4* r4 = (const float4*)row;
  float s0 = 0.f, s1 = 0.f, s2 = 0.f, s3 = 0.f;
#pragma unroll
  for (int q = 0; q < DIM / 4; ++q) {
    float4 v = r4[q];
    s0 = fmaf(v.x, v.x, s0); s1 = fmaf(v.y, v.y, s1);
    s2 = fmaf(v.z, v.z, s2); s3 = fmaf(v.w, v.w, s3);
  }
  *dst = (s0 + s1) + (s2 + s3);
}

// ---------------------------------------------------------------------------
// x_training -> hi/lo bf16 B-fragments in MFMA-linear order.
// Fragment f = tile*2 + ks (tile = n/16, ks = k/32). Lane l of fragment f
// holds x[tile*16 + (l&15)][ks*32 + (l>>4)*8 + j], j=0..7 (16B per lane).
// ---------------------------------------------------------------------------
__global__ __launch_bounds__(256) void k_xfrag(const float* __restrict__ xt,
                                               u16* __restrict__ xh,
                                               u16* __restrict__ xl) {
  int tid = blockIdx.x * 256 + threadIdx.x;  // (NTRAIN/16)*2*64 threads
  int frag = tid >> 6, lane = tid & 63;
  int tile = frag >> 1, ks = frag & 1;
  int lr = lane & 15, lg = lane >> 4;
  const float* src = xt + (size_t)(tile * 16 + lr) * DIM + ks * 32 + lg * 8;
  unsigned h[8], l[8];
#pragma unroll
  for (int j = 0; j < 8; ++j) {
    float v = src[j];
    u16 hb = f2bf(v);
    float rem = v - bf2f(hb);
    h[j] = hb;
    l[j] = f2bf(rem);
  }
  uint4 uh, ul;
  uh.x = h[0] | (h[1] << 16); uh.y = h[2] | (h[3] << 16);
  uh.z = h[4] | (h[5] << 16); uh.w = h[6] | (h[7] << 16);
  ul.x = l[0] | (l[1] << 16); ul.y = l[2] | (l[3] << 16);
  ul.z = l[4] | (l[5] << 16); ul.w = l[6] | (l[7] << 16);
  ((uint4*)xh)[(size_t)frag * 64 + lane] = uh;
  ((uint4*)xl)[(size_t)frag * 64 + lane] = ul;
}

// ---------------------------------------------------------------------------
// V = [1 | y | 0pad] (16 cols) -> bf16 B-fragments for the PV mfma.
// Block blk covers n = blk*32..+31. Lane l holds V[blk*32 + (l>>4)*8 + j][l&15].
// ---------------------------------------------------------------------------
__global__ __launch_bounds__(256) void k_yfrag(const float* __restrict__ yt,
                                               u16* __restrict__ yv) {
  int tid = blockIdx.x * 256 + threadIdx.x;  // (NTRAIN/32)*64 threads
  int blk = tid >> 6, lane = tid & 63;
  int col = lane & 15, lg = lane >> 4;
  int n = blk * 32 + lg * 8;
  unsigned e[8];
#pragma unroll
  for (int j = 0; j < 8; ++j) {
    float v = (col == 0) ? 1.0f : ((col < 9) ? yt[(size_t)(n + j) * ODIM + (col - 1)] : 0.0f);
    e[j] = f2bf(v);
  }
  uint4 u;
  u.x = e[0] | (e[1] << 16); u.y = e[2] | (e[3] << 16);
  u.z = e[4] | (e[5] << 16); u.w = e[6] | (e[7] << 16);
  ((uint4*)yv)[(size_t)blk * 64 + lane] = u;
}

// ---------------------------------------------------------------------------
// Pass 1: MFMA attention-style. Block = 4 waves x 64 m-rows = 256 m-rows.
// Wave handles 4 m-tiles (16x16), iterating 32 training rows per step:
//   S = A.X^T via bf16 hi/lo split (3 MFMAs per K-step), elementwise
//   w = exp(-beta*sqrt(b2+x2-2S)), P transposed via per-wave LDS (pad 20),
//   PV += P.V via one MFMA. Partials out per n-chunk.
// ---------------------------------------------------------------------------
__global__ __launch_bounds__(256, 2) void grnn_pass1(
    const float* __restrict__ batches,
    const u16* __restrict__ xh, const u16* __restrict__ xl,
    const u16* __restrict__ yv,
    const float* __restrict__ beta,
    const float* __restrict__ x2, const float* __restrict__ b2,
    float* __restrict__ partial, int chunk_n) {
  __shared__ float plds[4 * 2 * 320];  // per-wave [2 t][16 m][20 pad] fp32
  const int w = threadIdx.x >> 6, lane = threadIdx.x & 63;
  const int lr = lane & 15, lg = lane >> 4;
  const int m0 = blockIdx.x * 256 + w * 64;
  const int c = blockIdx.y;
  const int n0 = c * chunk_n;

  // A fragments (hi/lo) for 4 m-tiles x 2 ksteps, converted once.
  short8 ah[4][2], al[4][2];
#pragma unroll
  for (int mt = 0; mt < 4; ++mt)
#pragma unroll
    for (int ks = 0; ks < 2; ++ks) {
      const float* src = batches + (size_t)(m0 + mt * 16 + lr) * DIM + ks * 32 + lg * 8;
      float4 v0 = *(const float4*)(src);
      float4 v1 = *(const float4*)(src + 4);
      float vv[8] = {v0.x, v0.y, v0.z, v0.w, v1.x, v1.y, v1.z, v1.w};
      short8 hh, ll;
#pragma unroll
      for (int j = 0; j < 8; ++j) {
        u16 hb = f2bf(vv[j]);
        hh[j] = (short)hb;
        ll[j] = (short)f2bf(vv[j] - bf2f(hb));
      }
      ah[mt][ks] = hh;
      al[mt][ks] = ll;
    }

  // b2 for this lane's C rows (row = lg*4 + r within each tile).
  float b2v[4][4];
#pragma unroll
  for (int mt = 0; mt < 4; ++mt)
#pragma unroll
    for (int r = 0; r < 4; ++r)
      b2v[mt][r] = b2[m0 + mt * 16 + lg * 4 + r];

  f32x4 pv[4];
#pragma unroll
  for (int mt = 0; mt < 4; ++mt) pv[mt] = (f32x4){0.f, 0.f, 0.f, 0.f};

  const uint4* xh4 = (const uint4*)xh;
  const uint4* xl4 = (const uint4*)xl;
  const uint4* yv4 = (const uint4*)yv;
  float* pl = plds + w * 640;

  for (int nb = n0; nb < n0 + chunk_n; nb += 32) {
    // B fragments for this 32-n slab (hi/lo, 2 n-tiles x 2 ksteps) + V frag.
    short8 bh[2][2], bl[2][2];
#pragma unroll
    for (int t = 0; t < 2; ++t)
#pragma unroll
      for (int ks = 0; ks < 2; ++ks) {
        size_t f = ((size_t)(nb >> 4) + t) * 2 + ks;
        bh[t][ks] = __builtin_bit_cast(short8, xh4[f * 64 + lane]);
        bl[t][ks] = __builtin_bit_cast(short8, xl4[f * 64 + lane]);
      }
    short8 vf = __builtin_bit_cast(short8, yv4[((size_t)(nb >> 5)) * 64 + lane]);
    float x2n[2], nbeta[2];
#pragma unroll
    for (int t = 0; t < 2; ++t) {
      x2n[t] = x2[nb + t * 16 + lr];
      nbeta[t] = -beta[nb + t * 16 + lr];
    }

    // S tiles: 8 independent accumulators, 24 MFMAs round-robin for ILP.
    f32x4 s[4][2];
#pragma unroll
    for (int mt = 0; mt < 4; ++mt)
#pragma unroll
      for (int t = 0; t < 2; ++t) s[mt][t] = (f32x4){0.f, 0.f, 0.f, 0.f};
#pragma unroll
    for (int ks = 0; ks < 2; ++ks)
#pragma unroll
      for (int mt = 0; mt < 4; ++mt)
#pragma unroll
        for (int t = 0; t < 2; ++t) {
          s[mt][t] = mfma16(ah[mt][ks], bh[t][ks], s[mt][t]);
          s[mt][t] = mfma16(ah[mt][ks], bl[t][ks], s[mt][t]);
          s[mt][t] = mfma16(al[mt][ks], bh[t][ks], s[mt][t]);
        }

#pragma unroll
    for (int mt = 0; mt < 4; ++mt) {
      // w = exp(-beta * sqrt(max(b2 + x2 - 2S, 0))), scatter into LDS [t][m][20].
#pragma unroll
      for (int t = 0; t < 2; ++t)
#pragma unroll
        for (int r = 0; r < 4; ++r) {
          float sq = fmaf(-2.f, s[mt][t][r], b2v[mt][r] + x2n[t]);
          sq = fmaxf(sq, 0.f);
          float d = __builtin_amdgcn_sqrtf(sq);
          float wv = __expf(nbeta[t] * d);
          pl[t * 320 + (lg * 4 + r) * 20 + lr] = wv;
        }
      // Read back in PV A-fragment layout: row=lr, k=lg*8+j over the 32 n.
      int rbase = (lg >> 1) * 320 + lr * 20 + (lg & 1) * 8;
      f32x4 p0 = *(f32x4*)&pl[rbase];
      f32x4 p1 = *(f32x4*)&pl[rbase + 4];
      short8 pa;
#pragma unroll
      for (int j = 0; j < 4; ++j) {
        pa[j] = (short)f2bf(p0[j]);
        pa[4 + j] = (short)f2bf(p1[j]);
      }
      pv[mt] = mfma16(pa, vf, pv[mt]);
    }
  }

  // Epilogue: PV tile col 0 = sum(w), cols 1..8 = sum(w*y).
  float* pc = partial + (size_t)c * 9 * BATCH;
  if (lr < 9) {
#pragma unroll
    for (int mt = 0; mt < 4; ++mt)
#pragma unroll
      for (int r = 0; r < 4; ++r)
        pc[(size_t)lr * BATCH + (m0 + mt * 16 + lg * 4 + r)] = pv[mt][r];
  }
}

// ---------------------------------------------------------------------------
// Pass 2: reduce chunks, divide.
// ---------------------------------------------------------------------------
__global__ __launch_bounds__(256) void grnn_pass2(const float* __restrict__ partial,
                                                  float* __restrict__ out, int nc) {
  int b = blockIdx.x * 256 + threadIdx.x;
  float s1 = 0.f;
  float s2[ODIM];
#pragma unroll
  for (int j = 0; j < ODIM; ++j) s2[j] = 0.f;
  for (int cc = 0; cc < nc; ++cc) {
    const float* p = partial + (size_t)cc * 9 * BATCH;
    s1 += p[b];
#pragma unroll
    for (int j = 0; j < ODIM; ++j) s2[j] += p[(size_t)(j + 1) * BATCH + b];
  }
  const float inv = 1.f / s1;
#pragma unroll
  for (int j = 0; j < ODIM; ++j) out[(size_t)b * ODIM + j] = s2[j] * inv;
}

// ---------------------------------------------------------------------------
extern "C" void kernel_launch(void* const* d_in, const int* in_sizes, int n_in,
                              void* d_out, int out_size, void* d_ws, size_t ws_size,
                              hipStream_t stream) {
  const float* batches = (const float*)d_in[0];  // [8192, 64]
  const float* xt      = (const float*)d_in[1];  // [16384, 64]
  const float* yt      = (const float*)d_in[2];  // [16384, 8]
  const float* beta    = (const float*)d_in[3];  // [1, 16384]
  float* out = (float*)d_out;                    // [8192, 8]

  // Workspace carve (all section sizes are multiples of 256 B).
  const size_t xh_b = (size_t)NTRAIN * DIM * 2;            // 2 MB
  const size_t yv_b = (size_t)(NTRAIN / 32) * 64 * 8 * 2;  // 512 KB
  const size_t x2_b = (size_t)NTRAIN * 4;
  const size_t b2_b = (size_t)BATCH * 4;
  const size_t fixed = 2 * xh_b + yv_b + x2_b + b2_b;
  const size_t per_chunk = (size_t)9 * BATCH * 4;          // 288 KB

  int nc = 16;
  while (nc > 1 && fixed + (size_t)nc * per_chunk > ws_size) nc >>= 1;
  const int chunk_n = NTRAIN / nc;

  char* p = (char*)d_ws;
  u16* xh = (u16*)p;            p += xh_b;
  u16* xl = (u16*)p;            p += xh_b;
  u16* yv = (u16*)p;            p += yv_b;
  float* x2 = (float*)p;        p += x2_b;
  float* b2 = (float*)p;        p += b2_b;
  float* partial = (float*)p;

  k_norm<<<(BATCH + NTRAIN) / 256, 256, 0, stream>>>(batches, xt, b2, x2);
  k_xfrag<<<(NTRAIN / 16) * 2 * 64 / 256, 256, 0, stream>>>(xt, xh, xl);
  k_yfrag<<<(NTRAIN / 32) * 64 / 256, 256, 0, stream>>>(yt, yv);
  grnn_pass1<<<dim3(BATCH / 256, nc), 256, 0, stream>>>(
      batches, xh, xl, yv, beta, x2, b2, partial, chunk_n);
  grnn_pass2<<<BATCH / 256, 256, 0, stream>>>(partial, out, nc);
}